// Round 3
// baseline (81.888 us; speedup 1.0000x reference)
//
#include <hip/hip_runtime.h>

// BEV orthographic 3D Gaussian splatting, B=2, N=1024, D=32, H=W=200.
// Single kernel, one launch. Grid = (100, 1, 2), block = 512 (8 waves).
//  - Prepass: each block computes conic/radius for ALL 1024 gaussians of its
//    batch ONCE into an LDS SoA table (7 x float[1024], 28KB). Invalid
//    (op<=0.05 or det<=0) entries get r=-1e30 -> fail every bbox test.
//    Barrier-free (no compaction; entry index == gaussian index).
//  - Render: one wave = one 64x1 pixel strip (lane = x). 800 strips/batch,
//    one per wave. Scan LDS list in groups of 64 (conflict-free stride-4
//    reads), bbox-ballot, then bit-scan survivors with readlane broadcast.
//    Per-pixel exact front-to-back T; feats row loaded early at wave-uniform
//    address. Strips: x0 in {0,64,128,136} (strip 3 overlaps strip 2 on
//    x136..191 -> identical values recomputed/stored, benign).
//  - Stores: lane = consecutive x -> every per-channel store instruction is a
//    256B contiguous run (fully coalesced), vs 8x32B scatter before.
// Eps-stop: permanent per-pixel stop once T*(1-a) < 1e-4 (strict superset of
// reference's included set; bounded extra weight, passed at absmax 0.0039).
// Output: [bev (2,32,200,200) | mean_count scalar].

#define HH 200
#define WW 200
#define DD 32
#define NG 1024
#define BB 2
#define OUT_IMG (BB*DD*HH*WW)   // 2560000
#define ALPHA_MIN (1.0f/255.0f)

__device__ __forceinline__ float rlane(float x, int l) {
    return __uint_as_float(__builtin_amdgcn_readlane(__float_as_uint(x), l));
}

__global__ __launch_bounds__(512) void render_kernel(
    const float* __restrict__ feats,   // (B, NG, DD)
    const float* __restrict__ means,   // (B, NG, 3)
    const float* __restrict__ cov,     // (B, NG, 6)
    const float* __restrict__ opac,    // (B, NG)
    float* __restrict__ out)
{
    __shared__ float su[NG], sv[NG], sr[NG], sA[NG], sB[NG], sC[NG], sO[NG];
    __shared__ int csum[8];

    const int b    = blockIdx.z;
    const int tid  = threadIdx.x;
    const int lane = tid & 63;
    const int wid  = tid >> 6;

    // ---- prepass: conic+radius for all 1024 gaussians of batch b (SoA LDS)
    for (int r0 = 0; r0 < NG; r0 += 512) {
        const int gl = r0 + tid;
        const int g  = b*NG + gl;
        const float o   = opac[g];
        const float2 c01 = *(const float2*)(cov + (size_t)g*6);  // 8B-aligned
        const float c3  = cov[(size_t)g*6 + 3];
        const float m0  = means[(size_t)g*3 + 0];
        const float m1  = means[(size_t)g*3 + 1];
        const float av = 4.f*c3    + 0.3f;       // image-x variance
        const float cv = 4.f*c01.x + 0.3f;       // image-y variance
        const float bv = 4.f*c01.y;
        const float det = av*cv - bv*bv;
        float u=0.f, v=0.f, rr=-1e30f, A=0.f, Bc=0.f, Cc=0.f;
        if (o > 0.05f && det > 0.f) {
            u = -2.f*m1 + 100.f;
            v = -2.f*m0 + 100.f;
            const float qmax = 2.f*__logf(255.f*o);          // >0 since o>0.05
            const float htr = 0.5f*(av+cv), hdf = 0.5f*(av-cv);
            const float lmax = htr + sqrtf(hdf*hdf + bv*bv); // lmax(cov2D)
            rr = sqrtf(qmax*lmax) + 0.5f;                    // bound radius
            const float inv = 1.f/det;
            A = cv*inv; Bc = bv*inv; Cc = av*inv;
        }
        su[gl]=u; sv[gl]=v; sr[gl]=rr; sA[gl]=A; sB[gl]=Bc; sC[gl]=Cc; sO[gl]=o;
    }

    // ---- fused mean_count numerator (block (0, z=0) only), pre-barrier
    if (blockIdx.x == 0 && b == 0) {
        int s = 0;
        for (int i = tid; i < BB*NG; i += 512)
            s += (opac[i] > 0.05f) ? 1 : 0;
#pragma unroll
        for (int off = 32; off; off >>= 1) s += __shfl_down(s, off, 64);
        if (lane == 0) csum[wid] = s;
    }
    __syncthreads();
    if (blockIdx.x == 0 && b == 0 && tid == 0) {
        int t = 0;
#pragma unroll
        for (int wq = 0; wq < 8; ++wq) t += csum[wq];
        out[OUT_IMG] = (float)t * 0.5f;
    }

    // ---- render: one wave = one 64x1 strip
    const int S   = blockIdx.x*8 + wid;          // 0..799
    const int y   = S >> 2;
    const int sid = S & 3;
    const int x0  = (sid < 3) ? sid*64 : 136;    // strip 3 overlaps strip 2
    const float pxf = (float)(x0 + lane);
    const float pyf = (float)y;
    const float cxf = x0 + 31.5f;

    float4 acc[8];
#pragma unroll
    for (int j = 0; j < 8; ++j) acc[j] = make_float4(0.f,0.f,0.f,0.f);
    float T = 1.f;
    bool alive = true;
    const float* __restrict__ featsB = feats + (size_t)b * NG * DD;

    for (int e0 = 0; e0 < NG; e0 += 64) {
        if (__ballot(alive) == 0ull) break;      // whole strip saturated
        const int e = e0 + lane;
        const float ru = su[e], rv = sv[e], rr = sr[e];
        const float rA = sA[e], rB = sB[e], rC = sC[e], rO = sO[e];
        const bool flag = (fabsf(ru - cxf) <= 31.5f + rr) &&
                          (fabsf(rv - pyf) <= rr);
        unsigned long long mm = __ballot(flag);  // bit order == input order
        while (mm) {
            const int i = (int)__builtin_ctzll(mm);
            mm &= mm - 1ull;
            const int gi = e0 + i;               // wave-uniform
            const float4* __restrict__ col =
                (const float4*)(featsB + (size_t)gi * DD);
            const float4 f0=col[0], f1=col[1], f2=col[2], f3=col[3],
                         f4=col[4], f5=col[5], f6=col[6], f7=col[7];
            const float dx = rlane(ru, i) - pxf;
            const float dy = rlane(rv, i) - pyf;
            const float pw = fmaf(rlane(rB, i), dx*dy,
                              -0.5f*(rlane(rA, i)*dx*dx + rlane(rC, i)*dy*dy));
            const float alpha = fminf(0.99f, rlane(rO, i) * __expf(pw));
            const float om = 1.f - alpha;
            bool ok = alive && (pw <= 0.f) && (alpha >= ALPHA_MIN);
            if (ok && (T*om < 1e-4f)) { alive = false; ok = false; }
            if (ok) {
                const float w = alpha * T;
                acc[0].x=fmaf(w,f0.x,acc[0].x); acc[0].y=fmaf(w,f0.y,acc[0].y);
                acc[0].z=fmaf(w,f0.z,acc[0].z); acc[0].w=fmaf(w,f0.w,acc[0].w);
                acc[1].x=fmaf(w,f1.x,acc[1].x); acc[1].y=fmaf(w,f1.y,acc[1].y);
                acc[1].z=fmaf(w,f1.z,acc[1].z); acc[1].w=fmaf(w,f1.w,acc[1].w);
                acc[2].x=fmaf(w,f2.x,acc[2].x); acc[2].y=fmaf(w,f2.y,acc[2].y);
                acc[2].z=fmaf(w,f2.z,acc[2].z); acc[2].w=fmaf(w,f2.w,acc[2].w);
                acc[3].x=fmaf(w,f3.x,acc[3].x); acc[3].y=fmaf(w,f3.y,acc[3].y);
                acc[3].z=fmaf(w,f3.z,acc[3].z); acc[3].w=fmaf(w,f3.w,acc[3].w);
                acc[4].x=fmaf(w,f4.x,acc[4].x); acc[4].y=fmaf(w,f4.y,acc[4].y);
                acc[4].z=fmaf(w,f4.z,acc[4].z); acc[4].w=fmaf(w,f4.w,acc[4].w);
                acc[5].x=fmaf(w,f5.x,acc[5].x); acc[5].y=fmaf(w,f5.y,acc[5].y);
                acc[5].z=fmaf(w,f5.z,acc[5].z); acc[5].w=fmaf(w,f5.w,acc[5].w);
                acc[6].x=fmaf(w,f6.x,acc[6].x); acc[6].y=fmaf(w,f6.y,acc[6].y);
                acc[6].z=fmaf(w,f6.z,acc[6].z); acc[6].w=fmaf(w,f6.w,acc[6].w);
                acc[7].x=fmaf(w,f7.x,acc[7].x); acc[7].y=fmaf(w,f7.y,acc[7].y);
                acc[7].z=fmaf(w,f7.z,acc[7].z); acc[7].w=fmaf(w,f7.w,acc[7].w);
                T *= om;
            }
        }
    }

    // ---- stores: lane = consecutive x -> 256B contiguous per instruction
    const size_t base = (size_t)b * DD * (HH*WW) + (size_t)y * WW + x0 + lane;
#pragma unroll
    for (int j = 0; j < 8; ++j) {
        out[base + (size_t)(4*j+0)*(HH*WW)] = acc[j].x;
        out[base + (size_t)(4*j+1)*(HH*WW)] = acc[j].y;
        out[base + (size_t)(4*j+2)*(HH*WW)] = acc[j].z;
        out[base + (size_t)(4*j+3)*(HH*WW)] = acc[j].w;
    }
}

extern "C" void kernel_launch(void* const* d_in, const int* in_sizes, int n_in,
                              void* d_out, int out_size, void* d_ws, size_t ws_size,
                              hipStream_t stream) {
    const float* feats = (const float*)d_in[0];  // features (B,N,D)
    const float* means = (const float*)d_in[1];  // means3D  (B,N,3)
    const float* cvr   = (const float*)d_in[2];  // cov3D    (B,N,6)
    const float* opc   = (const float*)d_in[3];  // opacities(B,N,1)
    float* out = (float*)d_out;

    render_kernel<<<dim3(100, 1, BB), dim3(512), 0, stream>>>(
        feats, means, cvr, opc, out);
}

// Round 4
// 71.685 us; speedup vs baseline: 1.1423x; 1.1423x over previous
//
#include <hip/hip_runtime.h>

// BEV orthographic 3D Gaussian splatting, B=2, N=1024, D=32, H=W=200.
// Structure = R1 (best so far, 72.8us): one launch, 25x25x2 blocks, 8x8 tile,
// 4 waves/block each owning a 256-gaussian segment (2 ref 128-chunks),
// ballot-bit-scan + readlane broadcast, no barriers in the main loop,
// cross-wave combine via (img,T) associative op.
// R4 deltas (latency-targeted, math identical):
//  - ALL 4 groups' prepass loads (opac/cov/means, 20 VMEM) issued up front
//    into registers via static unroll -> 1 exposed latency window instead of 4.
//  - bbox cull uses squared compare dmax^2 <= qmax*lmax (drops one serial
//    sqrt from the dependent chain; same conservative bound, exact per-pixel
//    tests unchanged).
// Eps-stop semantics identical to R1 (segment-local T, 128-chunk boundary);
// passed at absmax 0.0039 in R1/R2/R3.
// Output: [bev (2,32,200,200) | mean_count scalar].

#define HH 200
#define WW 200
#define DD 32
#define NG 1024
#define BB 2
#define OUT_IMG (BB*DD*HH*WW)   // 2560000
#define NW 4                    // waves per block = gaussian segments
#define SEGG (NG/NW)            // 256 gaussians per segment
#define NGRP (SEGG/64)          // 4 groups of 64

__device__ __forceinline__ float rlane(float x, int l) {
    return __uint_as_float(__builtin_amdgcn_readlane(__float_as_uint(x), l));
}

__global__ __launch_bounds__(64*NW, 4) void render_kernel(
    const float* __restrict__ feats,   // (B, NG, DD)
    const float* __restrict__ means,   // (B, NG, 3)
    const float* __restrict__ cov,     // (B, NG, 6)
    const float* __restrict__ opac,    // (B, NG)
    float* __restrict__ out)
{
    __shared__ float4 simg[NW][64][8];   // swizzled ch4 slot = (c4+px)&7
    __shared__ float sT[NW][64];
    __shared__ float wsum[NW];

    const int b    = blockIdx.z;
    const int tid  = threadIdx.x;
    const int lane = tid & 63;
    const int wid  = tid >> 6;
    const float pxf = (float)(blockIdx.x*8 + (lane & 7));
    const float pyf = (float)(blockIdx.y*8 + (lane >> 3));
    const float cx  = blockIdx.x*8 + 3.5f;
    const float cy  = blockIdx.y*8 + 3.5f;

    const float* __restrict__ featsB = feats + (size_t)b * NG * DD;
    const int gB = b * NG;

    // ---- upfront prepass loads for all 4 groups (independent, issue together)
    float o_[NGRP], c0_[NGRP], c1_[NGRP], c3_[NGRP], m0_[NGRP], m1_[NGRP];
#pragma unroll
    for (int k = 0; k < NGRP; ++k) {
        const int g = gB + wid*SEGG + k*64 + lane;
        o_[k] = opac[g];
        const float2 c01 = *(const float2*)(cov + (size_t)g*6);  // 8B-aligned
        c0_[k] = c01.x; c1_[k] = c01.y;
        c3_[k] = cov[(size_t)g*6 + 3];
        m0_[k] = means[(size_t)g*3 + 0];
        m1_[k] = means[(size_t)g*3 + 1];
    }

    float4 acc[8];
#pragma unroll
    for (int j = 0; j < 8; ++j) acc[j] = make_float4(0.f,0.f,0.f,0.f);
    float T = 1.f, P = 1.f;
    bool skip = false;

#pragma unroll
    for (int k = 0; k < NGRP; ++k) {
        const int gbase = wid*SEGG + k*64;       // segment-local base index
        const float o  = o_[k];
        const float av = 4.f*c3_[k] + 0.3f;      // image-x variance
        const float cv = 4.f*c0_[k] + 0.3f;      // image-y variance
        const float bv = 4.f*c1_[k];
        const float det = av*cv - bv*bv;
        bool flag = false;
        float u=0.f, v=0.f, A=0.f, Bc=0.f, Cc=0.f, pl=0.f;
        if (o > 0.05f && det > 0.f) {
            u = -2.f*m1_[k] + 100.f;
            v = -2.f*m0_[k] + 100.f;
            pl = -__logf(255.f*o);               // power floor for alpha>=1/255
            const float qmax = -2.f*pl;          // >0 since o>0.05
            const float htr = 0.5f*(av+cv), hdf = 0.5f*(av-cv);
            const float lmax = htr + sqrtf(hdf*hdf + bv*bv);  // lmax(cov2D)
            // old: max(|du|,|dv|) <= 3.5 + (sqrt(qmax*lmax)+0.5)
            const float dmx = fmaxf(fabsf(u - cx), fabsf(v - cy)) - 4.0f;
            if (dmx <= 0.f || dmx*dmx <= qmax*lmax) {
                const float inv = 1.f/det;       // exact division, rare path
                A = cv*inv; Bc = bv*inv; Cc = av*inv;
                flag = true;
            }
        }
        unsigned long long mm = __ballot(flag);  // bit order == index order
        if (!skip) {
            while (mm) {
                const int i = (int)__builtin_ctzll(mm);
                mm &= mm - 1ull;
                const float ui  = rlane(u,  i);
                const float vi  = rlane(v,  i);
                const float Ai  = rlane(A,  i);
                const float Bi  = rlane(Bc, i);
                const float Ci  = rlane(Cc, i);
                const float oi  = rlane(o,  i);
                const float pli = rlane(pl, i);
                const float dx = ui - pxf;
                const float dy = vi - pyf;
                const float pw = fmaf(Bi, dx*dy, -0.5f*(Ai*dx*dx + Ci*dy*dy));
                if (pw > 0.f) continue;                    // reference mask
                if (pw < pli - 1e-3f) continue;            // provably alpha<1/255
                const float alpha = fminf(0.99f, oi * __expf(pw));
                if (alpha < (1.f/255.f)) continue;         // exact check
                const float om = 1.f - alpha;
                const float tp = T * P;
                if (tp * om < 1e-4f) { skip = true; break; }  // chunk eps-stop
                const float w = alpha * tp;
                const float4* __restrict__ col =           // wave-uniform addr
                    (const float4*)(featsB + (size_t)(gbase + i) * DD);
#pragma unroll
                for (int j = 0; j < 8; ++j) {
                    const float4 c4 = col[j];
                    acc[j].x = fmaf(w, c4.x, acc[j].x);
                    acc[j].y = fmaf(w, c4.y, acc[j].y);
                    acc[j].z = fmaf(w, c4.z, acc[j].z);
                    acc[j].w = fmaf(w, c4.w, acc[j].w);
                }
                P *= om;
            }
        }
        if (k & 1) { T *= P; P = 1.f; skip = false; }   // 128-chunk boundary
    }

    // ---- cross-wave combine: img = sum_s prefixT_s * img_s
    sT[wid][lane] = T;
#pragma unroll
    for (int j = 0; j < 8; ++j)
        simg[wid][lane][(j + lane) & 7] = acc[j];        // bank-swizzled
    __syncthreads();

    {
        const int p   = tid & 63;                        // pixel within tile
        const int grp = tid >> 6;                        // channel-quad pair
        const float t0 = sT[0][p], t1 = sT[1][p], t2 = sT[2][p];
        const float pf1 = t0, pf2 = t0*t1, pf3 = pf2*t2;
        const int ppx = blockIdx.x*8 + (p & 7);
        const int ppy = blockIdx.y*8 + (p >> 3);
        const size_t base = (size_t)b * DD * (HH*WW) + (size_t)ppy * WW + ppx;
#pragma unroll
        for (int q = 0; q < 2; ++q) {
            const int c4 = grp*2 + q;
            const int slot = (c4 + p) & 7;
            const float4 r0 = simg[0][p][slot];
            const float4 r1 = simg[1][p][slot];
            const float4 r2 = simg[2][p][slot];
            const float4 r3 = simg[3][p][slot];
            float4 ov;
            ov.x = fmaf(pf3, r3.x, fmaf(pf2, r2.x, fmaf(pf1, r1.x, r0.x)));
            ov.y = fmaf(pf3, r3.y, fmaf(pf2, r2.y, fmaf(pf1, r1.y, r0.y)));
            ov.z = fmaf(pf3, r3.z, fmaf(pf2, r2.z, fmaf(pf1, r1.z, r0.z)));
            ov.w = fmaf(pf3, r3.w, fmaf(pf2, r2.w, fmaf(pf1, r1.w, r0.w)));
            out[base + (size_t)(c4*4+0)*(HH*WW)] = ov.x;
            out[base + (size_t)(c4*4+1)*(HH*WW)] = ov.y;
            out[base + (size_t)(c4*4+2)*(HH*WW)] = ov.z;
            out[base + (size_t)(c4*4+3)*(HH*WW)] = ov.w;
        }
    }

    // ---- fused mean_count (one block)
    if (blockIdx.x == 0 && blockIdx.y == 0 && b == 0) {
        float s = 0.f;
        for (int i = tid; i < BB*NG; i += 64*NW)
            s += (opac[i] > 0.05f) ? 1.f : 0.f;
#pragma unroll
        for (int off = 32; off > 0; off >>= 1)
            s += __shfl_down(s, off, 64);
        if (lane == 0) wsum[wid] = s;
        __syncthreads();
        if (tid == 0)
            out[OUT_IMG] = (wsum[0]+wsum[1]+wsum[2]+wsum[3]) * (1.f/(float)BB);
    }
}

extern "C" void kernel_launch(void* const* d_in, const int* in_sizes, int n_in,
                              void* d_out, int out_size, void* d_ws, size_t ws_size,
                              hipStream_t stream) {
    const float* feats = (const float*)d_in[0];  // features (B,N,D)
    const float* means = (const float*)d_in[1];  // means3D  (B,N,3)
    const float* cvr   = (const float*)d_in[2];  // cov3D    (B,N,6)
    const float* opc   = (const float*)d_in[3];  // opacities(B,N,1)
    float* out = (float*)d_out;

    render_kernel<<<dim3(WW/8, HH/8, BB), dim3(64*NW), 0, stream>>>(
        feats, means, cvr, opc, out);
}